// Round 6
// baseline (225.671 us; speedup 1.0000x reference)
//
#include <hip/hip_runtime.h>

// Seq2SeqLSTM: H=64, F=8, T=512, P=64, B=1024, fp32 in/out.
// R18 = R16 champion + two issue-path cuts (R17 zero-row reads REVERTED: -2.4M
// conflicts but +4us -> conflicts are latency-shadowed, not on CP):
//  (1) x REGISTER ROTATION: x(t+1) preloaded into a VGPR one step early; its
//      LDS read latency spans the whole previous step.
//  (2) px FOLD (R15's verified Tg-in-K packing, WITHOUT R15's poison): the 4
//      pchain MFMAs become ONE px MFMA issued INSIDE the post-barrier
//      ds_read-wait window (A-operand is the preloaded register -> nothing to
//      wait on). k=Tg*8+f; A[m=4q'+Tg][k]=(q==col&3)?x[col>>2][f]:0;
//      B[k][n]=Wih[(q*64+u)*8+f]*sc(q); C=0. D row=4q+r -> P4[r] = gate-r
//      x-contribution for this lane's cell. NO splat: qgates C-init is the
//      static biasv quad (loop-invariant, decoder-proven pattern) and P4[Tg]
//      enters as ONE scalar add at each gate's spine head (+4cy CP).
//      MFMA/step: 12 -> 9 (8 on the issue path, 1 hidden in the window).
//  (3) decoder fc-shadow MFMAs moved after the h-write (off the cellf issue
//      path; they only feed predbuf).
// Structure: MB=4 over 256 blocks; lane (q,col) owns cell (batch q, unit
// wv*16+col); batch b at A-row 4b so C/D row=4q+0 puts gates in acc[.][0];
// qgates chained pairs g,g,i,i,f,f,o,o; fused-rcp cell with med3 guard; fp16
// weights/h/x pre-scaled by log2e (2*log2e for g); decoder folded W'.
// REVERTED (measured): R13 h-write swizzle (+7.6us), R14 VALU pdot (+25us),
// R15 bundle (+110us: ROWS=68 alignment + splat chain), R17 zero-row (+4us).

#define Hh 64
#define Ff 8
#define Tt 512
#define Pp 64
#define BATCH 1024
#define MB 4
#define NBLK (BATCH / MB)   // 256 blocks
#define ROWS 72             // halves per A row (64 + 8 pad)
#define ABUF (16 * ROWS + 64)
#define XSTRIDE 32          // halves per x step-row: 4 batches * 8

typedef __attribute__((ext_vector_type(8))) _Float16 half8;
typedef __attribute__((ext_vector_type(4))) _Float16 half4;
typedef __attribute__((ext_vector_type(4))) float f32x4;

#define LOG2E  1.44269504088896340736f
#define K2LOG2 2.88538008177792681472f   // 2*log2e

#define MFMA16(a, b, c) __builtin_amdgcn_mfma_f32_16x16x32_f16(a, b, c, 0, 0, 0)

__device__ __forceinline__ float rcp_(float x)  { return __builtin_amdgcn_rcpf(x); }
__device__ __forceinline__ float exp2_(float x) { return __builtin_amdgcn_exp2f(x); }
// A-row swizzle (halves): rows 4b (writers) keep offset 0.
__device__ __forceinline__ int arow_base(int m) { return m * ROWS + (m & 3) * 16; }

// B-fragments: 4 gate tiles, fp16, log2e-pre-scaled (2*log2e for g-gate).
// B layout (16x16x32): lane holds B[k = kc*32 + q*8 + j][n = col].
__device__ __forceinline__ void load_wfrags(
    const float* __restrict__ Whh, int wv, int q, int col,
    half8 w0[4], half8 w1[4])
{
    #pragma unroll
    for (int Tg = 0; Tg < 4; ++Tg) {
        int g = Tg * 64 + wv * 16 + col;
        float sc = (Tg == 2) ? K2LOG2 : LOG2E;
        const float* r0 = Whh + g * 64 + q * 8;
        #pragma unroll
        for (int j = 0; j < 8; ++j) {
            w0[Tg][j] = (_Float16)(r0[j] * sc);
            w1[Tg][j] = (_Float16)(r0[32 + j] * sc);
        }
    }
}

// Gate MFMAs: accumulator-chained pairs, g-gate first (longest downstream dep).
// C-init = static bias quads (loop-invariant).
__device__ __forceinline__ void qgates(half8 a0, half8 a1,
    const half8 w0[4], const half8 w1[4], const f32x4 Ci[4], f32x4 Q[4])
{
    Q[2] = MFMA16(a0, w0[2], Ci[2]);
    Q[2] = MFMA16(a1, w1[2], Q[2]);
    Q[0] = MFMA16(a0, w0[0], Ci[0]);
    Q[0] = MFMA16(a1, w1[0], Q[0]);
    Q[1] = MFMA16(a0, w0[1], Ci[1]);
    Q[1] = MFMA16(a1, w1[1], Q[1]);
    Q[3] = MFMA16(a0, w0[3], Ci[3]);
    Q[3] = MFMA16(a1, w1[3], Q[3]);
}

// Fused-rcp cell with px contribution P4[Tg] added at each gate head.
// Spine: add -> eg -> it -> cS fma -> med3 -> ec -> rc -> fma -> cvt.
__device__ __forceinline__ float cellf3(const f32x4 Q[4], f32x4 P4, float& cS)
{
    float eg = exp2_(Q[2][0] + P4[2]);    // e^{2g} (g pre-scaled 2*log2e)
    float ei = exp2_(-(Q[0][0] + P4[0]));
    float it = (eg - 1.f) * rcp_((1.f + ei) * (1.f + eg));   // si*tanh(g)
    float ef = exp2_(-(Q[1][0] + P4[1]));
    float sf = rcp_(1.f + ef);
    float eo = exp2_(-(Q[3][0] + P4[3]));
    float so   = rcp_(1.f + eo);          // sigmoid(o), off-spine
    float m2so = -2.f * so;
    cS = __builtin_fmaf(sf, cS, K2LOG2 * it);                // cS = 2*log2e*c
    float cc = __builtin_amdgcn_fmed3f(cS, -60.f, 60.f);     // exp2 guard
    float ec = exp2_(cc);                                    // e^{2c}
    float rc = rcp_(1.f + ec);
    return __builtin_fmaf(m2so, rc, so);  // so*tanh(c) = so*(1 - 2/(1+e^{2c}))
}

// Decoder variant: x folded into weights, no P4.
__device__ __forceinline__ float cellf(const f32x4 Q[4], float& cS)
{
    float eg = exp2_(Q[2][0]);
    float ei = exp2_(-Q[0][0]);
    float it = (eg - 1.f) * rcp_((1.f + ei) * (1.f + eg));
    float ef = exp2_(-Q[1][0]);
    float sf = rcp_(1.f + ef);
    float eo = exp2_(-Q[3][0]);
    float so   = rcp_(1.f + eo);
    float m2so = -2.f * so;
    cS = __builtin_fmaf(sf, cS, K2LOG2 * it);
    float cc = __builtin_amdgcn_fmed3f(cS, -60.f, 60.f);
    float ec = exp2_(cc);
    float rc = rcp_(1.f + ec);
    return __builtin_fmaf(m2so, rc, so);
}

__global__ __launch_bounds__(256, 1)
void seq2seq_v18(const float* __restrict__ x_seq,
                 const float* __restrict__ eWih, const float* __restrict__ eWhh,
                 const float* __restrict__ ebih, const float* __restrict__ ebhh,
                 const float* __restrict__ dWih, const float* __restrict__ dWhh,
                 const float* __restrict__ dbih, const float* __restrict__ dbhh,
                 const float* __restrict__ fcW,  const float* __restrict__ fcb,
                 float* __restrict__ out)
{
    __shared__ __align__(16) _Float16 xs[(Tt + 2) * XSTRIDE];  // 32.9 KB; predbuf alias
    __shared__ __align__(16) _Float16 A0[ABUF];
    __shared__ __align__(16) _Float16 A1[ABUF];

    const int tid  = threadIdx.x;
    const int wv   = tid >> 6;
    const int lane = tid & 63;
    const int q    = lane >> 4;
    const int col  = lane & 15;
    const int u    = wv * 16 + col;
    const int b0   = blockIdx.x * MB;
    const bool selq = (q == (col & 3));   // px A-mask (R15-verified)
    const half8 hz = {};
    const f32x4 Zv = {0.f, 0.f, 0.f, 0.f};

    half8 w0[4], w1[4];
    load_wfrags(eWhh, wv, q, col, w0, w1);
    // qgates C-init: bias quads (only slot 0 is consumed downstream)
    f32x4 biasv[4];
    #pragma unroll
    for (int Tg = 0; Tg < 4; ++Tg) {
        int g = Tg * 64 + u;
        float sc = (Tg == 2) ? K2LOG2 : LOG2E;
        float bv = (ebih[g] + ebhh[g]) * sc;
        biasv[Tg] = (f32x4){bv, bv, bv, bv};
    }
    // px B-fragment: Bx[j] = Wih[(q*64+u)][j] * sc(q)   (lane-static)
    half8 Bx;
    #pragma unroll
    for (int j = 0; j < 8; ++j)
        Bx[j] = (_Float16)(eWih[(q * 64 + u) * 8 + j] * ((q == 2) ? K2LOG2 : LOG2E));

    // init: zero A buffers + xs pad rows, stage x (fp32 -> fp16)
    { int* Z0 = (int*)A0; int* Z1 = (int*)A1;
      for (int i = tid; i < ABUF / 2; i += 256) { Z0[i] = 0; Z1[i] = 0; } }
    if (tid < 32) ((int*)xs)[Tt * 16 + tid] = 0;         // zero 2 pad rows
    for (int i = tid; i < MB * Tt * 2; i += 256) {       // 4096 float4s
        int b   = i >> 10;
        int rem = i & 1023;
        int t   = rem >> 1;
        int f4  = (rem & 1) * 4;
        const float* src = x_seq + ((size_t)(b0 + b) * Tt + t) * Ff + f4;
        half4 s = { (_Float16)src[0], (_Float16)src[1], (_Float16)src[2], (_Float16)src[3] };
        *(half4*)(&xs[t * XSTRIDE + b * 8 + f4]) = s;
    }
    __syncthreads();                                     // staging visible

    // per-lane hoisted pointers (R12/R16 addressing, swizzled A reads)
    const _Float16* arA = A0 + arow_base(col) + q * 8;
    const _Float16* arB = A1 + arow_base(col) + q * 8;
    _Float16* hwA = A0 + 4 * q * ROWS + u;
    _Float16* hwB = A1 + 4 * q * ROWS + u;
    const _Float16* xq = xs + (col >> 2) * 8;            // x walker (broadcast groups)

    float cS = 0.f;
    // x register pipeline: P4a = px(x(0)); xvA holds x(1).
    f32x4 P4a, P4b;
    half8 xvA, xvB;
    {   half8 xv0 = *(const half8*)(xq); xq += XSTRIDE;  // x(0)
        xvA        = *(const half8*)(xq); xq += XSTRIDE; // x(1)
        P4a = MFMA16(selq ? xv0 : hz, Bx, Zv); }

    // ============ encoder: 512 transitions, 2 per barrier pair ============
    for (int t = 0; t < Tt; t += 2) {
        __syncthreads();                                 // h(t) visible (A0)
        {   // transition t: h(t) -> h(t+1), consumes P4a (x(t)), makes P4b (x(t+1))
            half8 a0 = *(const half8*)(arA);
            half8 a1 = *(const half8*)(arA + 32);
            P4b = MFMA16(selq ? xvA : hz, Bx, Zv);       // px in read-wait window
            xvB = *(const half8*)(xq); xq += XSTRIDE;    // x(t+2), latency spans step
            f32x4 Q[4];
            qgates(a0, a1, w0, w1, biasv, Q);
            float hn = cellf3(Q, P4a, cS);
            *hwB = (_Float16)hn;                         // h(t+1) -> A1
        }
        __syncthreads();                                 // h(t+1) visible (A1)
        {   // transition t+1: consumes P4b, makes P4a (x(t+2))
            half8 a0 = *(const half8*)(arB);
            half8 a1 = *(const half8*)(arB + 32);
            P4a = MFMA16(selq ? xvB : hz, Bx, Zv);
            xvA = *(const half8*)(xq); xq += XSTRIDE;    // x(t+3) (pad rows at end)
            f32x4 Q[4];
            qgates(a0, a1, w0, w1, biasv, Q);
            float hn = cellf3(Q, P4b, cS);
            *hwA = (_Float16)hn;                         // h(t+2) -> A0
        }
    }
    // after loop: H_0 (encoder final h) in A0.

    // ================= decoder setup =================
    half8 axl = *(const half8*)(xs + (Tt - 1) * XSTRIDE + (col >> 2) * 8);

    // Plain decoder weights (step 0 only) + folded weights W' (steps 1..63).
    half8 wp0[4], wp1[4];
    f32x4 biasp[4];
    #pragma unroll
    for (int Tg = 0; Tg < 4; ++Tg) {
        int g = Tg * 64 + u;
        float sc = (Tg == 2) ? K2LOG2 : LOG2E;
        #pragma unroll
        for (int j = 0; j < 8; ++j) {
            int k0 = q * 8 + j;
            float v0 = dWhh[g * 64 + k0];
            float v1 = dWhh[g * 64 + 32 + k0];
            w0[Tg][j] = (_Float16)(v0 * sc);             // plain (step 0)
            w1[Tg][j] = (_Float16)(v1 * sc);
            float s0 = v0, s1 = v1;                      // fold: W' = Whh + Wih*fcW
            #pragma unroll
            for (int f = 0; f < 8; ++f) {
                float wif = dWih[g * 8 + f];
                s0 = __builtin_fmaf(wif, fcW[f * 64 + k0], s0);
                s1 = __builtin_fmaf(wif, fcW[f * 64 + 32 + k0], s1);
            }
            wp0[Tg][j] = (_Float16)(s0 * sc);
            wp1[Tg][j] = (_Float16)(s1 * sc);
        }
        float bb = dbih[g] + dbhh[g];
        float bp = bb;                                   // b' = b + Wih*fcb
        #pragma unroll
        for (int f = 0; f < 8; ++f) bp = __builtin_fmaf(dWih[g * 8 + f], fcb[f], bp);
        biasv[Tg] = (f32x4){bb * sc, bb * sc, bb * sc, bb * sc};
        biasp[Tg] = (f32x4){bp * sc, bp * sc, bp * sc, bp * sc};
    }
    // px fragment for decoder step 0 (x = x_last, dWih)
    #pragma unroll
    for (int j = 0; j < 8; ++j)
        Bx[j] = (_Float16)(dWih[(q * 64 + u) * 8 + j] * ((q == 2) ? K2LOG2 : LOG2E));
    // fc fragments: pred[b][f] = sum_u h[b][u]*fcW[f][u] + fcb[f]
    half8 wf0, wf1;
    f32x4 biasf;
    {
        #pragma unroll
        for (int j = 0; j < 8; ++j) {
            wf0[j] = (col < 8) ? (_Float16)fcW[col * 64 + q * 8 + j]      : (_Float16)0.f;
            wf1[j] = (col < 8) ? (_Float16)fcW[col * 64 + 32 + q * 8 + j] : (_Float16)0.f;
        }
        float fb = (col < 8) ? fcb[col] : 0.f;
        biasf = (f32x4){fb, fb, fb, fb};
    }

    float* predbuf = (float*)xs;                         // 8 KB alias over dead xs
    const bool pw = (wv == 0) && (col < 8);              // pred writer lanes

    // ---- decoder step 0: plain path, x = x_last; px hoisted off-CP ----
    P4a = MFMA16(selq ? axl : hz, Bx, Zv);
    __syncthreads();                                     // H_0 visible (A0)
    {
        half8 a0 = *(const half8*)(arA);
        half8 a1 = *(const half8*)(arA + 32);
        f32x4 Q[4];
        qgates(a0, a1, w0, w1, biasv, Q);
        float hn = cellf3(Q, P4a, cS);
        *hwB = (_Float16)hn;                             // H_1 -> A1
    }

    // ---- decoder steps 1..63: pure h-recurrence (folded W'), pred in shadow ----
    for (int p = 1; p < Pp; ++p) {
        __syncthreads();                                 // H_p visible
        const _Float16* ar = (p & 1) ? arB : arA;
        _Float16*       hw = (p & 1) ? hwA : hwB;
        half8 a0 = *(const half8*)(ar);
        half8 a1 = *(const half8*)(ar + 32);
        f32x4 Q[4];
        qgates(a0, a1, wp0, wp1, biasp, Q);              // CP: same as encoder
        float hn = cellf(Q, cS);
        *hw = (_Float16)hn;                              // H_{p+1}
        // shadow: pred(p-1) = fc(H_p), AFTER the write (off the cellf path)
        f32x4 F = MFMA16(a0, wf0, biasf);
        F       = MFMA16(a1, wf1, F);
        if (pw) predbuf[q * (Pp * Ff) + (p - 1) * Ff + col] = F[0];
    }

    // ---- epilogue: pred(63) = fc(H_64) (H_64 in A0: p=63 odd wrote hwA) ----
    __syncthreads();
    {
        half8 a0 = *(const half8*)(arA);
        half8 a1 = *(const half8*)(arA + 32);
        f32x4 F = MFMA16(a0, wf0, biasf);
        F       = MFMA16(a1, wf1, F);
        if (pw) predbuf[q * (Pp * Ff) + (Pp - 1) * Ff + col] = F[0];
    }
    __syncthreads();

    // ================= flush preds: LDS -> global, coalesced float4 =================
    {
        f32x4* out4 = (f32x4*)out + (size_t)b0 * (Pp * Ff / 4);
        const f32x4* pb4 = (const f32x4*)predbuf;
        for (int i = tid; i < MB * Pp * Ff / 4; i += 256)
            out4[i] = pb4[i];
    }
}

extern "C" void kernel_launch(void* const* d_in, const int* in_sizes, int n_in,
                              void* d_out, int out_size, void* d_ws, size_t ws_size,
                              hipStream_t stream) {
    (void)in_sizes; (void)n_in; (void)d_ws; (void)ws_size; (void)out_size;
    hipLaunchKernelGGL(seq2seq_v18, dim3(NBLK), dim3(256), 0, stream,
                       (const float*)d_in[0],
                       (const float*)d_in[1], (const float*)d_in[2],
                       (const float*)d_in[3], (const float*)d_in[4],
                       (const float*)d_in[5], (const float*)d_in[6],
                       (const float*)d_in[7], (const float*)d_in[8],
                       (const float*)d_in[9], (const float*)d_in[10],
                       (float*)d_out);
}